// Round 1
// baseline (821.019 us; speedup 1.0000x reference)
//
#include <hip/hip_runtime.h>
#include <hip/hip_bf16.h>

// Problem constants (compile-time so the GEMM addressing strength-reduces)
#define OUT_F 11008   // N
#define IN_F  4096    // K
#define M_DIM 4096    // 4 * 1024

typedef __attribute__((ext_vector_type(8))) short bf16x8;          // MFMA A/B frag (4 VGPRs)
typedef __attribute__((ext_vector_type(4))) float f32x4;           // MFMA C/D frag
typedef __attribute__((ext_vector_type(8))) unsigned short us8;    // 16B of bf16 bits

// ---------------------------------------------------------------------------
// Kernel 1: x fp32 -> bf16 (round-to-nearest-even), 8 elems/thread
// ---------------------------------------------------------------------------
__device__ __forceinline__ unsigned short f2bf_rne(float f) {
    unsigned u = __builtin_bit_cast(unsigned, f);
    u += 0x7fffu + ((u >> 16) & 1u);
    return (unsigned short)(u >> 16);
}

__global__ void cvt_x_kernel(const float* __restrict__ x,
                             unsigned short* __restrict__ xb) {
    size_t i = ((size_t)blockIdx.x * blockDim.x + threadIdx.x) * 8;
    float4 a = *(const float4*)(x + i);
    float4 b = *(const float4*)(x + i + 4);
    us8 o;
    o[0] = f2bf_rne(a.x); o[1] = f2bf_rne(a.y);
    o[2] = f2bf_rne(a.z); o[3] = f2bf_rne(a.w);
    o[4] = f2bf_rne(b.x); o[5] = f2bf_rne(b.y);
    o[6] = f2bf_rne(b.z); o[7] = f2bf_rne(b.w);
    *(us8*)(xb + i) = o;
}

// ---------------------------------------------------------------------------
// Kernel 2: unpack 2-bit weights -> bf16 [OUT_F][IN_F] (the GEMM's B^T layout)
// field t in {0,1,2,3} -> value t-1 in {-1,0,1,2} -> bf16 bit pattern via
// a 64-bit in-register LUT: {0xBF80, 0x0000, 0x3F80, 0x4000}
// ---------------------------------------------------------------------------
__global__ void unpack_w_kernel(const int* __restrict__ pw,
                                unsigned short* __restrict__ wb) {
    size_t i = (size_t)blockIdx.x * blockDim.x + threadIdx.x; // 2 packed ints/thread
    int2 v = *(const int2*)(pw + i * 2);
    const unsigned long long LUT = 0x40003F800000BF80ull;
    us8 o;
#pragma unroll
    for (int j = 0; j < 4; j++) {
        o[j]     = (unsigned short)(LUT >> (((v.x >> (2 * j)) & 3) * 16));
        o[4 + j] = (unsigned short)(LUT >> (((v.y >> (2 * j)) & 3) * 16));
    }
    *(us8*)(wb + i * 8) = o;
}

// ---------------------------------------------------------------------------
// Kernel 3: m97-structure bf16 GEMM, C[M][N] = A[M][K] * B[N][K]^T * scale
// 128x128 tile, BK=32, 4 waves in 2x2 (64x64 each = 4x4 MFMA 16x16x32 tiles),
// global->LDS staging via global_load_lds width=16 (wave-uniform base +
// lane*16 contiguous; LDS layout must match exactly -> no padding).
// ---------------------------------------------------------------------------
__global__ __launch_bounds__(256) void gemm_kernel(
    const unsigned short* __restrict__ A,   // [M_DIM][IN_F] bf16 bits
    const unsigned short* __restrict__ B,   // [OUT_F][IN_F] bf16 bits (B^T)
    float* __restrict__ C,                  // [M_DIM][OUT_F]
    const float* __restrict__ scale_ptr) {
    constexpr int K = IN_F;
    constexpr int N = OUT_F;

    __shared__ unsigned short sA[128 * 32]; // 8 KB
    __shared__ unsigned short sB[128 * 32]; // 8 KB

    const int tid  = threadIdx.x;
    const int wave = tid >> 6;
    const int lane = tid & 63;
    const int bn = blockIdx.x;
    const int bm = blockIdx.y;
    const int wm = (wave >> 1) * 64;  // wave's row offset in tile
    const int wn = (wave & 1) * 64;   // wave's col offset in tile

    // staging: 8 chunks of 1024B per tile; wave handles chunks {2w, 2w+1}
    // lane l in a chunk: row = chunk*16 + l/4, k-col = (l%4)*8
    const int srow = lane >> 2;
    const int scol = (lane & 3) * 8;

    const unsigned short* Ag = A + (size_t)bm * 128 * K;
    const unsigned short* Bg = B + (size_t)bn * 128 * K;

    f32x4 acc[4][4];
#pragma unroll
    for (int i = 0; i < 4; i++)
#pragma unroll
        for (int j = 0; j < 4; j++) acc[i][j] = (f32x4){0.f, 0.f, 0.f, 0.f};

    const int quad = lane >> 4;   // k-quad for A/B frags, row-quad for C
    const int mrow = lane & 15;   // m (A) / n (B) / col (C)

    for (int k0 = 0; k0 < K; k0 += 32) {
        __syncthreads();  // previous tile's MFMAs done before overwrite
#pragma unroll
        for (int c = 0; c < 2; c++) {
            const int chunk = wave * 2 + c;
            const int row = chunk * 16 + srow;
            __builtin_amdgcn_global_load_lds(
                (const __attribute__((address_space(1))) void*)(Ag + (size_t)row * K + k0 + scol),
                (__attribute__((address_space(3))) void*)(sA + chunk * 512),
                16, 0, 0);
        }
#pragma unroll
        for (int c = 0; c < 2; c++) {
            const int chunk = wave * 2 + c;
            const int row = chunk * 16 + srow;
            __builtin_amdgcn_global_load_lds(
                (const __attribute__((address_space(1))) void*)(Bg + (size_t)row * K + k0 + scol),
                (__attribute__((address_space(3))) void*)(sB + chunk * 512),
                16, 0, 0);
        }
        __syncthreads();  // staging drained (compiler emits vmcnt(0) before barrier)

        // LDS -> frags: A[m=lane&15][k=quad*8+j], B^T[n=lane&15][k=quad*8+j]
        bf16x8 af[4], bfg[4];
#pragma unroll
        for (int t = 0; t < 4; t++) {
            af[t]  = *(const bf16x8*)(sA + (wm + t * 16 + mrow) * 32 + quad * 8);
            bfg[t] = *(const bf16x8*)(sB + (wn + t * 16 + mrow) * 32 + quad * 8);
        }
#pragma unroll
        for (int i = 0; i < 4; i++)
#pragma unroll
            for (int j = 0; j < 4; j++)
                acc[i][j] = __builtin_amdgcn_mfma_f32_16x16x32_bf16(
                    af[i], bfg[j], acc[i][j], 0, 0, 0);
    }

    // Epilogue: C/D layout col=lane&15, row=quad*4+reg  (verified mapping)
    const float scale = *scale_ptr;
    float* Cg = C + (size_t)bm * 128 * N + (size_t)bn * 128;
#pragma unroll
    for (int i = 0; i < 4; i++) {
#pragma unroll
        for (int j = 0; j < 4; j++) {
#pragma unroll
            for (int r = 0; r < 4; r++) {
                const int row = wm + i * 16 + quad * 4 + r;
                const int col = wn + j * 16 + mrow;
                Cg[(size_t)row * N + col] = acc[i][j][r] * scale;
            }
        }
    }
}

// ---------------------------------------------------------------------------
// Launch
// ---------------------------------------------------------------------------
extern "C" void kernel_launch(void* const* d_in, const int* in_sizes, int n_in,
                              void* d_out, int out_size, void* d_ws, size_t ws_size,
                              hipStream_t stream) {
    const float* x   = (const float*)d_in[0];     // [4,1024,4096] fp32
    const int* pw    = (const int*)d_in[1];       // [11008*4096/4] int32 (byte values)
    const float* wsc = (const float*)d_in[2];     // [1] fp32

    float* out = (float*)d_out;                   // [4,1024,11008] fp32

    // workspace layout: A_bf16 (32 MiB) | W_bf16 (86 MiB)  => ~118 MiB total
    unsigned short* xb = (unsigned short*)d_ws;
    unsigned short* wb = (unsigned short*)((char*)d_ws + (size_t)M_DIM * IN_F * 2);

    // x convert: 16,777,216 elems / 8 per thread = 2,097,152 threads
    cvt_x_kernel<<<8192, 256, 0, stream>>>(x, xb);

    // unpack: 11,272,192 packed ints / 2 per thread = 5,636,096 threads
    unpack_w_kernel<<<22016, 256, 0, stream>>>(pw, wb);

    // GEMM: grid (N/128, M/128) = (86, 32)
    gemm_kernel<<<dim3(86, 32), 256, 0, stream>>>(xb, wb, out, wsc);
}